// Round 10
// baseline (859.750 us; speedup 1.0000x reference)
//
#include <hip/hip_runtime.h>
#include <hip/hip_fp16.h>
#include <cmath>

#define HDIM 1024
#define TPB 512
#define NWG 256
#define M4 4194304ull                   // elements per 4096x1024 matrix
#define WS_WOFF 327680ull               // byte offset of fp16 weights in ws
#define CVT_TOTAL 42991616ull           // 10*M4 + 1024*1024
#define WS_NEEDED (WS_WOFF + CVT_TOTAL * 2ull)
// ws layout: [4096,20480) master h0 (4 slots x 4KB tagged words);
// [20480,36864) master h1; [36864,45056) flag mirrors: mirror m (0..7) at
// 36864+m*1024, inside: stream*512 + slot*64 + checker*4 (int tag values).

typedef unsigned long long ulong64;
typedef unsigned int uint32;
typedef _Float16 h2f __attribute__((ext_vector_type(2)));

// ---- agent-scope relaxed atomics: L3 coherence point, no cache invalidation ----
__device__ __forceinline__ ulong64 ld_g8(const ulong64* p) {
  return __hip_atomic_load(p, __ATOMIC_RELAXED, __HIP_MEMORY_SCOPE_AGENT);
}
__device__ __forceinline__ void st_gu(uint32* p, uint32 v) {
  __hip_atomic_store(p, v, __ATOMIC_RELAXED, __HIP_MEMORY_SCOPE_AGENT);
}
__device__ __forceinline__ void st_gi(int* p, int v) {
  __hip_atomic_store(p, v, __ATOMIC_RELAXED, __HIP_MEMORY_SCOPE_AGENT);
}

__device__ __forceinline__ float sigm(float x) { return 1.f / (1.f + __expf(-x)); }
__device__ __forceinline__ float tanh_f(float x) {
  float e = __expf(2.f * x);
  return 1.f - 2.f / (e + 1.f);
}

__device__ __forceinline__ float f4dot(float4 wf, float4 xf, float acc) {
  union { float4 f; h2f h[4]; } w, x;
  w.f = wf; x.f = xf;
#pragma unroll
  for (int i = 0; i < 4; ++i) {
#if __has_builtin(__builtin_amdgcn_fdot2)
    acc = __builtin_amdgcn_fdot2(w.h[i], x.h[i], acc, false);
#else
    acc = fmaf((float)w.h[i].x, (float)x.h[i].x, acc);
    acc = fmaf((float)w.h[i].y, (float)x.h[i].y, acc);
#endif
  }
  return acc;
}

// ================= persistent dataflow LSTM, checker/flag broadcast =================
// 256 WGs x 512 threads. WG owns 4 cells; waves 0-3 layer1, 4-7 layer0 (+linear).
// 16-lane group g computes gate g. h words: (tag<<16)|fp16, 4 rotating slots in L3.
// WGs 0-7 are "checkers": wave0/1 hot-sweep a 512B slice of the h0/h1 slot; on
// completion they fan the tag to 8 mirrored flag lines. Consumer waves first try
// 2 speculative tag-verified reads of the data (fast path, skips the flag chain),
// then fall back to polling their 32B flag line + one verified read.
__global__ void __launch_bounds__(TPB, 2) rf16_kernel(
    const float* __restrict__ in_Wih0, const float* __restrict__ in_bih0, const float* __restrict__ in_bhh0,
    const float* __restrict__ in_bih1, const float* __restrict__ in_bhh1,
    const float* __restrict__ out_Wih0, const float* __restrict__ out_bih0, const float* __restrict__ out_bhh0,
    const float* __restrict__ out_bih1, const float* __restrict__ out_bhh1,
    const float* __restrict__ pr_bih0, const float* __restrict__ pr_bhh0,
    const float* __restrict__ pr_bih1, const float* __restrict__ pr_bhh1,
    const float* __restrict__ lin_b,
    const int* __restrict__ in_seq, const int* __restrict__ out_seq,
    float* __restrict__ out, float* __restrict__ ws)
{
  const int tid = threadIdx.x, wg = blockIdx.x;
  const int wv = tid >> 6, lane = tid & 63;
  const int grp = lane >> 4, gl = lane & 15;
  const int cell = (wg << 2) + (wv & 3);
  const bool isL1 = wv < 4;
  const int rowi = (grp << 10) + cell;
  const bool chkWG = (wg < 8);

  const __half* wb = (const __half*)((const char*)ws + WS_WOFF);
  // fp16 matrices: 0 in_Wih1, 1 in_Whh1, 2 in_Whh0, 3 out_Wih1, 4 out_Whh1,
  //                5 out_Whh0, 6 pr_Wih1, 7 pr_Whh1, 8 pr_Whh0, 9 pr_Wih0, 10 lin_W
  uint32* h0M = (uint32*)((char*)ws + 4096);
  uint32* h1M = (uint32*)((char*)ws + 20480);
  int* FL = (int*)((char*)ws + 36864);            // 8 mirrors x 1024B
  int* myFlag = FL + ((wg & 7) << 8);             // my mirror (ints)

  __shared__ __align__(16) ulong64 xaP[2][256], xbP[2][256];  // 2KB per buffer

  float c_reg = 0.f, pre0v = 0.f;
  float bA, bB, bC, lbias = 0.f;
  if (isL1) {
    bA = in_bih1[rowi] + in_bhh1[rowi];
    bB = out_bih1[rowi] + out_bhh1[rowi];
    bC = pr_bih1[rowi] + pr_bhh1[rowi];
  } else {
    bA = in_bih0[rowi] + in_bhh0[rowi];
    bB = out_bih0[rowi] + out_bhh0[rowi];
    bC = pr_bih0[rowi] + pr_bhh0[rowi];
    lbias = lin_b[cell];
  }

  int fail = 0;
  float4 wreg[16];
  float4 lw0, lw1;

  auto preload8 = [&](const __half* wrow, int base) {
    const float4* w4 = (const float4*)wrow;
#pragma unroll
    for (int j = 0; j < 8; ++j) wreg[base + j] = w4[j * 16 + gl];
  };
  auto dotx = [&](int base, const ulong64* xp, float acc) {
    const __half* x = (const __half*)xp;
#pragma unroll
    for (int j = 0; j < 8; ++j)
      acc = f4dot(wreg[base + j], *(const float4*)(x + (j * 16 + gl) * 8), acc);
    return acc;
  };
  auto red16 = [&](float v) {
#pragma unroll
    for (int o = 1; o < 16; o <<= 1) v += __shfl_xor(v, o, 64);
    return v;
  };
  auto wred64 = [&](float v) {
#pragma unroll
    for (int o = 1; o < 64; o <<= 1) v += __shfl_xor(v, o, 64);
    return v;
  };
  auto tags_ok = [&](const ulong64* d, int tag) {
    bool ok = true;
#pragma unroll
    for (int i = 0; i < 8; ++i)
      ok &= (((int)((d[i] >> 16) & 0xFFFF)) == tag) & (((int)(d[i] >> 48)) == tag);
    return ok;
  };
  auto pack_lds = [&](const ulong64* d, ulong64* dst) {
    uint32 q[8];
#pragma unroll
    for (int i = 0; i < 8; ++i)
      q[i] = (uint32)(d[i] & 0xFFFF) | ((uint32)((d[i] >> 32) & 0xFFFF) << 16);
    dst[4 * lane]     = (ulong64)q[0] | ((ulong64)q[1] << 32);
    dst[4 * lane + 1] = (ulong64)q[2] | ((ulong64)q[3] << 32);
    dst[4 * lane + 2] = (ulong64)q[4] | ((ulong64)q[5] << 32);
    dst[4 * lane + 3] = (ulong64)q[6] | ((ulong64)q[7] << 32);
  };
  // checker sweep + flag fanout + {speculative fast path | flag wait + read}
  auto fetch_pack = [&](const uint32* T, int stream, int tag, ulong64* dst) {
    if (fail) return;
    const int slot = tag & 3;
    if (chkWG) {
      // my 512B slice of this slot: lane reads one tagged 8B word
      const ulong64* sl = (const ulong64*)(T + (slot << 10)) + (wg << 6) + lane;
      int spins = 0;
      for (;;) {
        ulong64 w = ld_g8(sl);
        bool ok = (((int)((w >> 16) & 0xFFFF)) == tag) & (((int)(w >> 48)) == tag);
        if (__all(ok)) break;
        if (++spins > (1 << 20)) { fail = 1; break; }
      }
      if (!fail && lane < 8)   // fan my tag out to all 8 mirrors
        st_gi(FL + (lane << 8) + (stream << 7) + (slot << 4) + wg, tag);
    }
    const ulong64* src = (const ulong64*)(T + (slot << 10)) + (lane << 3);
    ulong64 d[8];
    // fast path: 2 speculative tag-verified reads (data usually already there)
#pragma unroll 1
    for (int t = 0; t < 2; ++t) {
#pragma unroll
      for (int i = 0; i < 8; ++i) d[i] = ld_g8(src + i);
      if (__all(tags_ok(d, tag))) { pack_lds(d, dst); return; }
    }
    // fallback: poll my mirror's 32B flag line (8 checker tags)
    {
      const ulong64* fp = (const ulong64*)(myFlag + (stream << 7) + (slot << 4));
      int spins = 0;
      for (;;) {
        ulong64 f0 = ld_g8(fp), f1 = ld_g8(fp + 1);
        ulong64 f2 = ld_g8(fp + 2), f3 = ld_g8(fp + 3);
        bool ok = (((int)f0) == tag) & (((int)(f0 >> 32)) == tag) &
                  (((int)f1) == tag) & (((int)(f1 >> 32)) == tag) &
                  (((int)f2) == tag) & (((int)(f2 >> 32)) == tag) &
                  (((int)f3) == tag) & (((int)(f3 >> 32)) == tag);
        if (ok) break;
        if (++spins > (1 << 20)) { fail = 1; return; }
        __builtin_amdgcn_s_sleep(1);
      }
    }
    // verified data read (passes first try after flag)
    int spins = 0;
    for (;;) {
#pragma unroll
      for (int i = 0; i < 8; ++i) d[i] = ld_g8(src + i);
      if (__all(tags_ok(d, tag))) break;
      if (++spins > (1 << 16)) { fail = 1; return; }
    }
    pack_lds(d, dst);
  };
  auto zero_pack = [&](ulong64* dst) {
#pragma unroll
    for (int i = 0; i < 4; ++i) dst[4 * lane + i] = 0ull;
  };
  // LSTM cell update; tagged fire-and-forget store to L3 master
  auto produce = [&](float v, uint32* T, int tag) {
    float gi = __shfl(v, 0, 64), gf = __shfl(v, 16, 64);
    float gc = __shfl(v, 32, 64), go = __shfl(v, 48, 64);
    float c2 = sigm(gf) * c_reg + sigm(gi) * tanh_f(gc);
    c_reg = c2;
    if (lane == 0) {
      uint32 w = ((uint32)tag << 16) | (uint32)__half_as_ushort(__float2half(sigm(go) * tanh_f(c2)));
      st_gu(T + ((tag & 3) << 10) + cell, w);
    }
  };

  // ---------- Stage 1: L0 computes h0(0) (h=0, c=0 -> bias + one-hot column) ----------
  if (!isL1) {
    int idx = in_seq[0];
    float v = bA + in_Wih0[(size_t)rowi * 128 + idx];
    produce(v, h0M, 1);
  }

  // ---------- Encoder phase-resident weights ----------
  if (isL1) {
    preload8(wb + 0 * M4 + (size_t)rowi * 1024, 0);   // in_Wih1
    preload8(wb + 1 * M4 + (size_t)rowi * 1024, 8);   // in_Whh1
  } else {
    preload8(wb + 2 * M4 + (size_t)rowi * 1024, 0);   // in_Whh0
  }

  // stages s=2..128: consume h0(t)[s-1], h1(t-1)[s-1]; produce h1(t)[s] / h0(t+1)[s]
#pragma unroll 1
  for (int s = 2; s <= 128; ++s) {
    if (s == 65 && !isL1) preload8(wb + 5 * M4 + (size_t)rowi * 1024, 0);  // out_Whh0
    if (s == 66 && isL1) {
      preload8(wb + 3 * M4 + (size_t)rowi * 1024, 0);  // out_Wih1
      preload8(wb + 4 * M4 + (size_t)rowi * 1024, 8);  // out_Whh1
    }
    float wcol = 0.f;
    if (!isL1) {
      int idx = (s < 65) ? in_seq[s - 1] : out_seq[s - 65];
      wcol = ((s < 65) ? in_Wih0 : out_Wih0)[(size_t)rowi * 128 + idx];
    }
    if (wv == 0) fetch_pack(h0M, 0, s - 1, xaP[s & 1]);
    if (wv == 1) {
      if (s == 2) zero_pack(xbP[0]);
      else fetch_pack(h1M, 1, s - 1, xbP[s & 1]);
    }
    __syncthreads();
    if (isL1) {
      float v = dotx(0, xaP[s & 1], 0.f);
      v = dotx(8, xbP[s & 1], v);
      v = red16(v) + ((s < 66) ? bA : bB);
      produce(v, h1M, s);
    } else {
      float v = red16(dotx(0, xaP[s & 1], 0.f)) + ((s < 65) ? bA : bB) + wcol;
      produce(v, h0M, s);
    }
  }

  // ---------- Stage 129: layer1[127] ----------
  if (wv == 0) fetch_pack(h0M, 0, 128, xaP[1]);
  if (wv == 1) fetch_pack(h1M, 1, 128, xbP[1]);
  __syncthreads();
  if (isL1) {
    float v = dotx(0, xaP[1], 0.f);
    v = dotx(8, xbP[1], v);
    v = red16(v) + bB;
    produce(v, h1M, 129);
  }

  // ---------- Stage 130: pre0 (constant decoder input) + decoder h0(128) ----------
  if (!isL1) {
    preload8(wb + 9 * M4 + (size_t)rowi * 1024, 0);   // pr_Wih0
    preload8(wb + 8 * M4 + (size_t)rowi * 1024, 8);   // pr_Whh0
  }
  if (wv == 0) fetch_pack(h0M, 0, 128, xaP[0]);
  if (wv == 1) fetch_pack(h1M, 1, 129, xbP[0]);
  __syncthreads();
  if (!isL1) {
    pre0v = red16(dotx(0, xbP[0], 0.f)) + bC;          // pr_Wih0 . h1(127) + bias
    float v = red16(dotx(8, xaP[0], 0.f)) + pre0v;     // + pr_Whh0 . h0(127)
    produce(v, h0M, 130);
  }

  // ---------- Decoder-resident weights ----------
  if (isL1) {
    preload8(wb + 6 * M4 + (size_t)rowi * 1024, 0);   // pr_Wih1
    preload8(wb + 7 * M4 + (size_t)rowi * 1024, 8);   // pr_Whh1
  } else {
#pragma unroll
    for (int j = 0; j < 8; ++j) wreg[j] = wreg[8 + j];  // pr_Whh0 -> base 0
    const float4* lwp = (const float4*)(wb + 10 * M4 + (size_t)cell * 1024);
    lw0 = lwp[lane * 2]; lw1 = lwp[lane * 2 + 1];
  }

  // stages s=131..162
#pragma unroll 1
  for (int s = 131; s <= 162; ++s) {
    const int tb = (s == 131) ? 129 : s - 1;
    if (wv == 0) fetch_pack(h0M, 0, s - 1, xaP[s & 1]);
    if (wv == 1) fetch_pack(h1M, 1, tb, xbP[s & 1]);
    __syncthreads();
    if (isL1) {
      float v = dotx(0, xaP[s & 1], 0.f);
      v = dotx(8, xbP[s & 1], v);
      v = red16(v) + bC;
      produce(v, h1M, s);
    } else {
      if (s >= 132) {
        const __half* x = (const __half*)xbP[s & 1];
        float a = f4dot(lw0, *(const float4*)(x + lane * 16), 0.f);
        a = f4dot(lw1, *(const float4*)(x + lane * 16 + 8), a);
        float r = wred64(a) + lbias;
        if (lane == 0) out[(size_t)(s - 132) * 1024 + cell] = r;
      }
      if (s <= 161) {
        float v = red16(dotx(0, xaP[s & 1], 0.f)) + pre0v;
        produce(v, h0M, s);
      }
    }
  }

  // ---------- Stage 163: final linear row 31 from h1(159) [tag 162] ----------
  if (wv == 1) fetch_pack(h1M, 1, 162, xbP[1]);
  __syncthreads();
  if (!isL1) {
    const __half* x = (const __half*)xbP[1];
    float a = f4dot(lw0, *(const float4*)(x + lane * 16), 0.f);
    a = f4dot(lw1, *(const float4*)(x + lane * 16 + 8), a);
    float r = wred64(a) + lbias;
    if (lane == 0) out[(size_t)31 * 1024 + cell] = r;
  }
}

// ================= fp32 -> fp16 weight conversion =================
struct CvtArgs { const float* s[11]; };

__global__ void __launch_bounds__(256) cvt_kernel(CvtArgs a, __half* dst) {
  size_t i = ((size_t)blockIdx.x * 256 + threadIdx.x) * 8;
  if (i >= CVT_TOTAL) return;
  const float* sp;
  if (i < 10 * M4) sp = a.s[i >> 22] + (i & (M4 - 1));
  else sp = a.s[10] + (i - 10 * M4);
  float4 f0 = ((const float4*)sp)[0];
  float4 f1 = ((const float4*)sp)[1];
  __half2 o[4];
  o[0] = __float22half2_rn(make_float2(f0.x, f0.y));
  o[1] = __float22half2_rn(make_float2(f0.z, f0.w));
  o[2] = __float22half2_rn(make_float2(f1.x, f1.y));
  o[3] = __float22half2_rn(make_float2(f1.z, f1.w));
  *((float4*)(dst + i)) = *(float4*)o;
}

extern "C" void kernel_launch(void* const* d_in, const int* in_sizes, int n_in,
                              void* d_out, int out_size, void* d_ws, size_t ws_size,
                              hipStream_t stream) {
  (void)in_sizes; (void)n_in; (void)out_size;
  if (ws_size < WS_NEEDED) return;
  // zero master slots + flag mirrors each launch/replay
  (void)hipMemsetAsync(d_ws, 0, 45056, stream);
  const float* F[26];
  for (int i = 0; i < 26; ++i) F[i] = (const float*)d_in[i];
  const int* iseq = (const int*)d_in[26];
  const int* oseq = (const int*)d_in[27];

  CvtArgs ca;
  ca.s[0] = F[4];  ca.s[1] = F[5];  ca.s[2] = F[1];   // in_Wih1, in_Whh1, in_Whh0
  ca.s[3] = F[12]; ca.s[4] = F[13]; ca.s[5] = F[9];   // out_Wih1, out_Whh1, out_Whh0
  ca.s[6] = F[20]; ca.s[7] = F[21]; ca.s[8] = F[17];  // pr_Wih1, pr_Whh1, pr_Whh0
  ca.s[9] = F[16]; ca.s[10] = F[24];                  // pr_Wih0, lin_W
  __half* wdst = (__half*)((char*)d_ws + WS_WOFF);
  cvt_kernel<<<dim3((unsigned)(CVT_TOTAL / 8 / 256)), dim3(256), 0, stream>>>(ca, wdst);
  rf16_kernel<<<dim3(NWG), dim3(TPB), 0, stream>>>(
      F[0], F[2], F[3], F[6], F[7],
      F[8], F[10], F[11], F[14], F[15],
      F[18], F[19], F[22], F[23],
      F[25], iseq, oseq, (float*)d_out, (float*)d_ws);
}

// Round 11
// 671.284 us; speedup vs baseline: 1.2808x; 1.2808x over previous
//
#include <hip/hip_runtime.h>
#include <hip/hip_fp16.h>
#include <cmath>

#define HDIM 1024
#define TPB 512
#define NWG 256
#define M4 4194304ull                   // elements per 4096x1024 matrix
#define WS_WOFF 327680ull               // byte offset of fp16 weights in ws
#define CVT_TOTAL 42991616ull           // 10*M4 + 1024*1024
#define WS_NEEDED (WS_WOFF + CVT_TOTAL * 2ull)
// ws layout: [4096,20480) master h0 (4 slots x 4KB tagged words);
// [20480,36864) master h1; [36864,167936) h0 mirrors (8 x 4 slots x 4KB);
// [167936,299008) h1 mirrors. Checkers republish verified data into mirrors.

typedef unsigned long long ulong64;
typedef unsigned int uint32;
typedef _Float16 h2f __attribute__((ext_vector_type(2)));

// ---- agent-scope relaxed atomics: L3 coherence point, no cache invalidation ----
__device__ __forceinline__ ulong64 ld_g8(const ulong64* p) {
  return __hip_atomic_load(p, __ATOMIC_RELAXED, __HIP_MEMORY_SCOPE_AGENT);
}
__device__ __forceinline__ void st_g8(ulong64* p, ulong64 v) {
  __hip_atomic_store(p, v, __ATOMIC_RELAXED, __HIP_MEMORY_SCOPE_AGENT);
}
__device__ __forceinline__ void st_gu(uint32* p, uint32 v) {
  __hip_atomic_store(p, v, __ATOMIC_RELAXED, __HIP_MEMORY_SCOPE_AGENT);
}

__device__ __forceinline__ float sigm(float x) { return 1.f / (1.f + __expf(-x)); }
__device__ __forceinline__ float tanh_f(float x) {
  float e = __expf(2.f * x);
  return 1.f - 2.f / (e + 1.f);
}

__device__ __forceinline__ float f4dot(float4 wf, float4 xf, float acc) {
  union { float4 f; h2f h[4]; } w, x;
  w.f = wf; x.f = xf;
#pragma unroll
  for (int i = 0; i < 4; ++i) {
#if __has_builtin(__builtin_amdgcn_fdot2)
    acc = __builtin_amdgcn_fdot2(w.h[i], x.h[i], acc, false);
#else
    acc = fmaf((float)w.h[i].x, (float)x.h[i].x, acc);
    acc = fmaf((float)w.h[i].y, (float)x.h[i].y, acc);
#endif
  }
  return acc;
}

// ================= persistent dataflow LSTM, checker data-republish =================
// 256 WGs x 512 threads. WG owns 4 cells; waves 0-3 layer1, 4-7 layer0 (+linear).
// 16-lane group g computes gate g. h words: (tag<<16)|fp16, 4 rotating slots in L3.
// WGs 0-7 are "checkers": wave0/1 hot-sweep a 512B slice of the h0/h1 master slot;
// on completion each lane BURSTS its verified 8B word to 8 mirror regions (full
// coalesced lines). Consumer waves poll ONLY their own mirror (wg&7) with
// tag-verified sweeps — the successful poll IS the data read (no flags).
__global__ void __launch_bounds__(TPB, 2) rf16_kernel(
    const float* __restrict__ in_Wih0, const float* __restrict__ in_bih0, const float* __restrict__ in_bhh0,
    const float* __restrict__ in_bih1, const float* __restrict__ in_bhh1,
    const float* __restrict__ out_Wih0, const float* __restrict__ out_bih0, const float* __restrict__ out_bhh0,
    const float* __restrict__ out_bih1, const float* __restrict__ out_bhh1,
    const float* __restrict__ pr_bih0, const float* __restrict__ pr_bhh0,
    const float* __restrict__ pr_bih1, const float* __restrict__ pr_bhh1,
    const float* __restrict__ lin_b,
    const int* __restrict__ in_seq, const int* __restrict__ out_seq,
    float* __restrict__ out, float* __restrict__ ws)
{
  const int tid = threadIdx.x, wg = blockIdx.x;
  const int wv = tid >> 6, lane = tid & 63;
  const int grp = lane >> 4, gl = lane & 15;
  const int cell = (wg << 2) + (wv & 3);
  const bool isL1 = wv < 4;
  const int rowi = (grp << 10) + cell;
  const bool chkWG = (wg < 8);

  const __half* wb = (const __half*)((const char*)ws + WS_WOFF);
  // fp16 matrices: 0 in_Wih1, 1 in_Whh1, 2 in_Whh0, 3 out_Wih1, 4 out_Whh1,
  //                5 out_Whh0, 6 pr_Wih1, 7 pr_Whh1, 8 pr_Whh0, 9 pr_Wih0, 10 lin_W
  uint32* h0M = (uint32*)((char*)ws + 4096);
  uint32* h1M = (uint32*)((char*)ws + 20480);
  ulong64* h0Mir = (ulong64*)((char*)ws + 36864);           // 8 mir x 4 slots x 4KB
  ulong64* h1Mir = (ulong64*)((char*)ws + 36864 + 131072);
  const int myMir = (wg & 7) << 11;                          // mirror offset (ulong64)

  __shared__ __align__(16) ulong64 xaP[2][256], xbP[2][256];

  float c_reg = 0.f, pre0v = 0.f;
  float bA, bB, bC, lbias = 0.f;
  if (isL1) {
    bA = in_bih1[rowi] + in_bhh1[rowi];
    bB = out_bih1[rowi] + out_bhh1[rowi];
    bC = pr_bih1[rowi] + pr_bhh1[rowi];
  } else {
    bA = in_bih0[rowi] + in_bhh0[rowi];
    bB = out_bih0[rowi] + out_bhh0[rowi];
    bC = pr_bih0[rowi] + pr_bhh0[rowi];
    lbias = lin_b[cell];
  }

  int fail = 0;
  float4 wreg[16];
  float4 lw0, lw1;

  auto preload8 = [&](const __half* wrow, int base) {
    const float4* w4 = (const float4*)wrow;
#pragma unroll
    for (int j = 0; j < 8; ++j) wreg[base + j] = w4[j * 16 + gl];
  };
  auto dotx = [&](int base, const ulong64* xp, float acc) {
    const __half* x = (const __half*)xp;
#pragma unroll
    for (int j = 0; j < 8; ++j)
      acc = f4dot(wreg[base + j], *(const float4*)(x + (j * 16 + gl) * 8), acc);
    return acc;
  };
  auto red16 = [&](float v) {
#pragma unroll
    for (int o = 1; o < 16; o <<= 1) v += __shfl_xor(v, o, 64);
    return v;
  };
  auto wred64 = [&](float v) {
#pragma unroll
    for (int o = 1; o < 64; o <<= 1) v += __shfl_xor(v, o, 64);
    return v;
  };
  auto tags_ok = [&](const ulong64* d, int tag) {
    bool ok = true;
#pragma unroll
    for (int i = 0; i < 8; ++i)
      ok &= (((int)((d[i] >> 16) & 0xFFFF)) == tag) & (((int)(d[i] >> 48)) == tag);
    return ok;
  };
  auto pack_lds = [&](const ulong64* d, ulong64* dst) {
    uint32 q[8];
#pragma unroll
    for (int i = 0; i < 8; ++i)
      q[i] = (uint32)(d[i] & 0xFFFF) | ((uint32)((d[i] >> 32) & 0xFFFF) << 16);
    dst[4 * lane]     = (ulong64)q[0] | ((ulong64)q[1] << 32);
    dst[4 * lane + 1] = (ulong64)q[2] | ((ulong64)q[3] << 32);
    dst[4 * lane + 2] = (ulong64)q[4] | ((ulong64)q[5] << 32);
    dst[4 * lane + 3] = (ulong64)q[6] | ((ulong64)q[7] << 32);
  };
  // checker: sweep my 512B master slice, then burst verified words to 8 mirrors.
  // consumer: tag-verified poll of my own (quiet) mirror slot = the data read.
  auto fetch_pack = [&](const uint32* T, ulong64* Mir, int tag, ulong64* dst) {
    if (fail) return;
    const int slot = tag & 3;
    if (chkWG) {
      const ulong64* sl = (const ulong64*)(T + (slot << 10)) + (wg << 6) + lane;
      ulong64 w = 0;
      int spins = 0;
      for (;;) {
        w = ld_g8(sl);
        bool ok = (((int)((w >> 16) & 0xFFFF)) == tag) & (((int)(w >> 48)) == tag);
        if (__all(ok)) break;
        if (++spins > (1 << 20)) { fail = 1; break; }
      }
      if (!fail) {
        const int widx = (slot << 9) + (wg << 6) + lane;
#pragma unroll
        for (int m = 0; m < 8; ++m)
          st_g8(Mir + (m << 11) + widx, w);
      }
    }
    const ulong64* src = Mir + myMir + (slot << 9) + (lane << 3);
    ulong64 d[8];
    int spins = 0;
    for (;;) {
#pragma unroll
      for (int i = 0; i < 8; ++i) d[i] = ld_g8(src + i);
      if (__all(tags_ok(d, tag))) break;
      if (++spins > (1 << 20)) { fail = 1; return; }
      __builtin_amdgcn_s_sleep(1);
    }
    pack_lds(d, dst);
  };
  auto zero_pack = [&](ulong64* dst) {
#pragma unroll
    for (int i = 0; i < 4; ++i) dst[4 * lane + i] = 0ull;
  };
  // LSTM cell update; tagged fire-and-forget store to L3 master (single store)
  auto produce = [&](float v, uint32* T, int tag) {
    float gi = __shfl(v, 0, 64), gf = __shfl(v, 16, 64);
    float gc = __shfl(v, 32, 64), go = __shfl(v, 48, 64);
    float c2 = sigm(gf) * c_reg + sigm(gi) * tanh_f(gc);
    c_reg = c2;
    if (lane == 0) {
      uint32 w = ((uint32)tag << 16) | (uint32)__half_as_ushort(__float2half(sigm(go) * tanh_f(c2)));
      st_gu(T + ((tag & 3) << 10) + cell, w);
    }
  };

  // ---------- Stage 1: L0 computes h0(0) (h=0, c=0 -> bias + one-hot column) ----------
  if (!isL1) {
    int idx = in_seq[0];
    float v = bA + in_Wih0[(size_t)rowi * 128 + idx];
    produce(v, h0M, 1);
  }

  // ---------- Encoder phase-resident weights ----------
  if (isL1) {
    preload8(wb + 0 * M4 + (size_t)rowi * 1024, 0);   // in_Wih1
    preload8(wb + 1 * M4 + (size_t)rowi * 1024, 8);   // in_Whh1
  } else {
    preload8(wb + 2 * M4 + (size_t)rowi * 1024, 0);   // in_Whh0
  }

  // stages s=2..128: consume h0(t)[s-1], h1(t-1)[s-1]; produce h1(t)[s] / h0(t+1)[s]
#pragma unroll 1
  for (int s = 2; s <= 128; ++s) {
    if (s == 65 && !isL1) preload8(wb + 5 * M4 + (size_t)rowi * 1024, 0);  // out_Whh0
    if (s == 66 && isL1) {
      preload8(wb + 3 * M4 + (size_t)rowi * 1024, 0);  // out_Wih1
      preload8(wb + 4 * M4 + (size_t)rowi * 1024, 8);  // out_Whh1
    }
    float wcol = 0.f;
    if (!isL1) {
      int idx = (s < 65) ? in_seq[s - 1] : out_seq[s - 65];
      wcol = ((s < 65) ? in_Wih0 : out_Wih0)[(size_t)rowi * 128 + idx];
    }
    if (wv == 0) fetch_pack(h0M, h0Mir, s - 1, xaP[s & 1]);
    if (wv == 1) {
      if (s == 2) zero_pack(xbP[0]);
      else fetch_pack(h1M, h1Mir, s - 1, xbP[s & 1]);
    }
    __syncthreads();
    if (isL1) {
      float v = dotx(0, xaP[s & 1], 0.f);
      v = dotx(8, xbP[s & 1], v);
      v = red16(v) + ((s < 66) ? bA : bB);
      produce(v, h1M, s);
    } else {
      float v = red16(dotx(0, xaP[s & 1], 0.f)) + ((s < 65) ? bA : bB) + wcol;
      produce(v, h0M, s);
    }
  }

  // ---------- Stage 129: layer1[127] ----------
  if (wv == 0) fetch_pack(h0M, h0Mir, 128, xaP[1]);
  if (wv == 1) fetch_pack(h1M, h1Mir, 128, xbP[1]);
  __syncthreads();
  if (isL1) {
    float v = dotx(0, xaP[1], 0.f);
    v = dotx(8, xbP[1], v);
    v = red16(v) + bB;
    produce(v, h1M, 129);
  }

  // ---------- Stage 130: pre0 (constant decoder input) + decoder h0(128) ----------
  if (!isL1) {
    preload8(wb + 9 * M4 + (size_t)rowi * 1024, 0);   // pr_Wih0
    preload8(wb + 8 * M4 + (size_t)rowi * 1024, 8);   // pr_Whh0
  }
  if (wv == 0) fetch_pack(h0M, h0Mir, 128, xaP[0]);
  if (wv == 1) fetch_pack(h1M, h1Mir, 129, xbP[0]);
  __syncthreads();
  if (!isL1) {
    pre0v = red16(dotx(0, xbP[0], 0.f)) + bC;          // pr_Wih0 . h1(127) + bias
    float v = red16(dotx(8, xaP[0], 0.f)) + pre0v;     // + pr_Whh0 . h0(127)
    produce(v, h0M, 130);
  }

  // ---------- Decoder-resident weights ----------
  if (isL1) {
    preload8(wb + 6 * M4 + (size_t)rowi * 1024, 0);   // pr_Wih1
    preload8(wb + 7 * M4 + (size_t)rowi * 1024, 8);   // pr_Whh1
  } else {
#pragma unroll
    for (int j = 0; j < 8; ++j) wreg[j] = wreg[8 + j];  // pr_Whh0 -> base 0
    const float4* lwp = (const float4*)(wb + 10 * M4 + (size_t)cell * 1024);
    lw0 = lwp[lane * 2]; lw1 = lwp[lane * 2 + 1];
  }

  // stages s=131..162
#pragma unroll 1
  for (int s = 131; s <= 162; ++s) {
    const int tb = (s == 131) ? 129 : s - 1;
    if (wv == 0) fetch_pack(h0M, h0Mir, s - 1, xaP[s & 1]);
    if (wv == 1) fetch_pack(h1M, h1Mir, tb, xbP[s & 1]);
    __syncthreads();
    if (isL1) {
      float v = dotx(0, xaP[s & 1], 0.f);
      v = dotx(8, xbP[s & 1], v);
      v = red16(v) + bC;
      produce(v, h1M, s);
    } else {
      if (s >= 132) {
        const __half* x = (const __half*)xbP[s & 1];
        float a = f4dot(lw0, *(const float4*)(x + lane * 16), 0.f);
        a = f4dot(lw1, *(const float4*)(x + lane * 16 + 8), a);
        float r = wred64(a) + lbias;
        if (lane == 0) out[(size_t)(s - 132) * 1024 + cell] = r;
      }
      if (s <= 161) {
        float v = red16(dotx(0, xaP[s & 1], 0.f)) + pre0v;
        produce(v, h0M, s);
      }
    }
  }

  // ---------- Stage 163: final linear row 31 from h1(159) [tag 162] ----------
  if (wv == 1) fetch_pack(h1M, h1Mir, 162, xbP[1]);
  __syncthreads();
  if (!isL1) {
    const __half* x = (const __half*)xbP[1];
    float a = f4dot(lw0, *(const float4*)(x + lane * 16), 0.f);
    a = f4dot(lw1, *(const float4*)(x + lane * 16 + 8), a);
    float r = wred64(a) + lbias;
    if (lane == 0) out[(size_t)31 * 1024 + cell] = r;
  }
}

// ================= fp32 -> fp16 weight conversion =================
struct CvtArgs { const float* s[11]; };

__global__ void __launch_bounds__(256) cvt_kernel(CvtArgs a, __half* dst) {
  size_t i = ((size_t)blockIdx.x * 256 + threadIdx.x) * 8;
  if (i >= CVT_TOTAL) return;
  const float* sp;
  if (i < 10 * M4) sp = a.s[i >> 22] + (i & (M4 - 1));
  else sp = a.s[10] + (i - 10 * M4);
  float4 f0 = ((const float4*)sp)[0];
  float4 f1 = ((const float4*)sp)[1];
  __half2 o[4];
  o[0] = __float22half2_rn(make_float2(f0.x, f0.y));
  o[1] = __float22half2_rn(make_float2(f0.z, f0.w));
  o[2] = __float22half2_rn(make_float2(f1.x, f1.y));
  o[3] = __float22half2_rn(make_float2(f1.z, f1.w));
  *((float4*)(dst + i)) = *(float4*)o;
}

extern "C" void kernel_launch(void* const* d_in, const int* in_sizes, int n_in,
                              void* d_out, int out_size, void* d_ws, size_t ws_size,
                              hipStream_t stream) {
  (void)in_sizes; (void)n_in; (void)out_size;
  if (ws_size < WS_NEEDED) return;
  // zero master slots + data mirrors each launch/replay
  (void)hipMemsetAsync(d_ws, 0, 299008, stream);
  const float* F[26];
  for (int i = 0; i < 26; ++i) F[i] = (const float*)d_in[i];
  const int* iseq = (const int*)d_in[26];
  const int* oseq = (const int*)d_in[27];

  CvtArgs ca;
  ca.s[0] = F[4];  ca.s[1] = F[5];  ca.s[2] = F[1];   // in_Wih1, in_Whh1, in_Whh0
  ca.s[3] = F[12]; ca.s[4] = F[13]; ca.s[5] = F[9];   // out_Wih1, out_Whh1, out_Whh0
  ca.s[6] = F[20]; ca.s[7] = F[21]; ca.s[8] = F[17];  // pr_Wih1, pr_Whh1, pr_Whh0
  ca.s[9] = F[16]; ca.s[10] = F[24];                  // pr_Wih0, lin_W
  __half* wdst = (__half*)((char*)d_ws + WS_WOFF);
  cvt_kernel<<<dim3((unsigned)(CVT_TOTAL / 8 / 256)), dim3(256), 0, stream>>>(ca, wdst);
  rf16_kernel<<<dim3(NWG), dim3(TPB), 0, stream>>>(
      F[0], F[2], F[3], F[6], F[7],
      F[8], F[10], F[11], F[14], F[15],
      F[18], F[19], F[22], F[23],
      F[25], iseq, oseq, (float*)d_out, (float*)d_ws);
}